// Round 1
// baseline (16725.197 us; speedup 1.0000x reference)
//
#include <hip/hip_runtime.h>

// Bidirectional (feature-reversed) 2-layer LSTM, persistent-wave design.
// 4 chains = (dir, layer); each chain = 32 one-wave blocks (64 thr).
// Per wave: weights for 4 gate-tiles x K=512 resident in 256 VGPRs (f16),
// c-state in 4 VGPRs, per-tick: 16 A-frag loads + 64 mfma_f32_16x16x32_f16.
// Cross-block sync: agent-scope acquire/release flags, 8-slot rotating h
// exchange buffers in d_ws (back-pressure keeps slot reuse race-free).

typedef _Float16 half8 __attribute__((ext_vector_type(8)));
typedef float f32x4 __attribute__((ext_vector_type(4)));

#define B_ 32
#define S_ 2048
#define D_ 256
#define H_ 256
#define G_ 1024
#define NSLOT 8
#define OUT0 (B_*S_*2*H_)   /* 33554432 */

__device__ __forceinline__ float sigmoidf_(float v){ return 1.f/(1.f+__expf(-v)); }
__device__ __forceinline__ float tanhf_(float v){ return 2.f/(1.f+__expf(-2.f*v)) - 1.f; }

// ws layout: [0,8192): flags (4 chains * 32 members, 64B stride)
//            [8192, 8192+512KB): hbuf: 4 chains * 8 slots * (32*256) f16
__global__ __launch_bounds__(256) void lstm_prep(const float* __restrict__ enc_h,
                                                 int* __restrict__ flags,
                                                 _Float16* __restrict__ hbuf)
{
  int idx = blockIdx.x*blockDim.x + threadIdx.x;
  if (idx < 4*32) flags[idx*16] = 0;
  for (int i = idx; i < 4*B_*H_; i += gridDim.x*blockDim.x) {
    int chain = i >> 13;      // / (32*256)
    int r     = i & 8191;
    int b     = r >> 8;
    int col   = r & 255;
    int dir   = chain >> 1;
    hbuf[(size_t)chain*(NSLOT*B_*H_) + r] = (_Float16)enc_h[b*(2*H_) + dir*H_ + col];
  }
}

__global__ __launch_bounds__(64,1) void lstm_main(
    const float* __restrict__ x,
    const float* __restrict__ enc_c,
    const float* __restrict__ Wih_f, const float* __restrict__ Whh_f,
    const float* __restrict__ bih_f, const float* __restrict__ bhh_f,
    const float* __restrict__ Wih_b, const float* __restrict__ Whh_b,
    const float* __restrict__ bih_b, const float* __restrict__ bhh_b,
    float* __restrict__ out,
    int* __restrict__ flags,
    _Float16* __restrict__ hbuf)
{
  const int bid   = blockIdx.x;   // 0..127
  const int chain = bid & 3;      // dir*2 + layer
  const int w     = bid >> 2;     // member 0..31
  const int dir   = chain >> 1;
  const int layer = chain & 1;
  const int m     = w & 1;        // M-tile (batch 16-row half)
  const int c0    = (w >> 1) << 4;// h-column base (16 cols)
  const int lane  = threadIdx.x;  // 64
  const int quad  = lane >> 4;
  const int lq    = lane & 15;

  const float* Wih = dir ? Wih_b : Wih_f;
  const float* Whh = dir ? Whh_b : Whh_f;
  const float* bih = dir ? bih_b : bih_f;
  const float* bhh = dir ? bhh_b : bhh_f;

  // ---- resident B-fragments: bf[q][kk], q=gate(i,f,g,o), kk=K-frag ----
  // B[k][n]: lane -> n = q*256 + c0 + lq, k = kk*32 + quad*8 + j (j=0..7)
  half8 bf[4][16];
#pragma unroll
  for (int q = 0; q < 4; ++q) {
    const int n_g = q*256 + c0 + lq;
    const float* wihr = Wih + (size_t)layer*G_*256 + (size_t)n_g*256 + quad*8;
    const float* whhr = Whh + (size_t)layer*G_*256 + (size_t)n_g*256 + quad*8;
#pragma unroll
    for (int kk = 0; kk < 16; ++kk) {
      const float* src = (kk < 8) ? (wihr + kk*32) : (whhr + (kk-8)*32);
      f32x4 w0 = *(const f32x4*)src;
      f32x4 w1 = *(const f32x4*)(src+4);
      half8 hv;
      hv[0]=(_Float16)w0[0]; hv[1]=(_Float16)w0[1]; hv[2]=(_Float16)w0[2]; hv[3]=(_Float16)w0[3];
      hv[4]=(_Float16)w1[0]; hv[5]=(_Float16)w1[1]; hv[6]=(_Float16)w1[2]; hv[7]=(_Float16)w1[3];
      bf[q][kk] = hv;
    }
  }

  float bias[4];
#pragma unroll
  for (int q = 0; q < 4; ++q) {
    const int n_g = q*256 + c0 + lq;
    bias[q] = bih[layer*G_ + n_g] + bhh[layer*G_ + n_g];
  }

  // c-state in C/D layout: row = m*16 + quad*4 + r, col = c0+lq
  f32x4 cst;
#pragma unroll
  for (int r = 0; r < 4; ++r) {
    const int b = m*16 + quad*4 + r;
    cst[r] = enc_c[b*(2*H_) + dir*H_ + c0 + lq];
  }

  _Float16* hbufOwn      = hbuf + (size_t)chain*(NSLOT*B_*H_);
  const _Float16* hbufL0 = hbuf + (size_t)(dir*2)*(NSLOT*B_*H_);
  int* myFlag = flags + (size_t)(chain*32 + w)*16;
  const int otherChain = (layer == 1) ? (dir*2) : (dir*2 + 1);
  const int* spinPtr = (lane < 32)
      ? (const int*)(flags + (size_t)(chain*32 + (lane & 31))*16)
      : (const int*)(flags + (size_t)(otherChain*32 + (lane & 31))*16);

  const int arow = m*16 + lq;              // A-row (batch) this lane feeds
  const float* xrowBase = x + (size_t)arow*S_*D_;

  bool dead = false;

  for (int t = 0; t < S_; ++t) {
    half8 ain[8], arec[8];

    if (layer == 0) {
      // x loads issued BEFORE the flag wait (independent of recurrence)
      const float* xr = xrowBase + (size_t)t*D_;
#pragma unroll
      for (int kk = 0; kk < 8; ++kk) {
        const int k = kk*32 + quad*8;
        half8 hv;
        if (dir == 0) {
          f32x4 a0 = *(const f32x4*)(xr + k);
          f32x4 a1 = *(const f32x4*)(xr + k + 4);
          hv[0]=(_Float16)a0[0]; hv[1]=(_Float16)a0[1]; hv[2]=(_Float16)a0[2]; hv[3]=(_Float16)a0[3];
          hv[4]=(_Float16)a1[0]; hv[5]=(_Float16)a1[1]; hv[6]=(_Float16)a1[2]; hv[7]=(_Float16)a1[3];
        } else {
          // feature-reversed: u[k+j] = x[255-k-j] = p[7-j], p = xr + 248 - k
          const float* p = xr + (248 - k);
          f32x4 a0 = *(const f32x4*)p;
          f32x4 a1 = *(const f32x4*)(p + 4);
          hv[0]=(_Float16)a1[3]; hv[1]=(_Float16)a1[2]; hv[2]=(_Float16)a1[1]; hv[3]=(_Float16)a1[0];
          hv[4]=(_Float16)a0[3]; hv[5]=(_Float16)a0[2]; hv[6]=(_Float16)a0[1]; hv[7]=(_Float16)a0[0];
        }
        ain[kk] = hv;
      }
      // wait: own group >= t (h(t-1) ready); L1 >= t-7 (slot back-pressure)
      {
        const int tgt = (lane < 32) ? t : (t - 7);
        int guard = 0;
        while (true) {
          int v = __hip_atomic_load(spinPtr, __ATOMIC_RELAXED, __HIP_MEMORY_SCOPE_AGENT);
          if (__all(v >= tgt)) break;
          if (++guard > (1 << 20)) { dead = true; break; }
          __builtin_amdgcn_s_sleep(1);
        }
      }
      if (dead) break;
      __builtin_amdgcn_fence(__ATOMIC_ACQUIRE, "agent");
      const _Float16* hs = hbufOwn + (size_t)(t & 7)*(B_*H_) + (size_t)arow*H_ + quad*8;
#pragma unroll
      for (int kk = 0; kk < 8; ++kk)
        arec[kk] = *(const half8*)(hs + kk*32);
    } else {
      // wait: own >= t (h1(t-1)); L0 >= t+1 (h0(t) published)
      {
        const int tgt = (lane < 32) ? t : (t + 1);
        int guard = 0;
        while (true) {
          int v = __hip_atomic_load(spinPtr, __ATOMIC_RELAXED, __HIP_MEMORY_SCOPE_AGENT);
          if (__all(v >= tgt)) break;
          if (++guard > (1 << 20)) { dead = true; break; }
          __builtin_amdgcn_s_sleep(1);
        }
      }
      if (dead) break;
      __builtin_amdgcn_fence(__ATOMIC_ACQUIRE, "agent");
      const _Float16* hi = hbufL0 + (size_t)((t+1) & 7)*(B_*H_) + (size_t)arow*H_ + quad*8;
      const _Float16* hr = hbufOwn + (size_t)(t & 7)*(B_*H_) + (size_t)arow*H_ + quad*8;
#pragma unroll
      for (int kk = 0; kk < 8; ++kk) {
        ain[kk]  = *(const half8*)(hi + kk*32);
        arec[kk] = *(const half8*)(hr + kk*32);
      }
    }

    f32x4 acc0 = {bias[0],bias[0],bias[0],bias[0]};
    f32x4 acc1 = {bias[1],bias[1],bias[1],bias[1]};
    f32x4 acc2 = {bias[2],bias[2],bias[2],bias[2]};
    f32x4 acc3 = {bias[3],bias[3],bias[3],bias[3]};
#pragma unroll
    for (int kk = 0; kk < 8; ++kk) {
      acc0 = __builtin_amdgcn_mfma_f32_16x16x32_f16(ain[kk], bf[0][kk], acc0, 0,0,0);
      acc1 = __builtin_amdgcn_mfma_f32_16x16x32_f16(ain[kk], bf[1][kk], acc1, 0,0,0);
      acc2 = __builtin_amdgcn_mfma_f32_16x16x32_f16(ain[kk], bf[2][kk], acc2, 0,0,0);
      acc3 = __builtin_amdgcn_mfma_f32_16x16x32_f16(ain[kk], bf[3][kk], acc3, 0,0,0);
    }
#pragma unroll
    for (int kk = 0; kk < 8; ++kk) {
      acc0 = __builtin_amdgcn_mfma_f32_16x16x32_f16(arec[kk], bf[0][kk+8], acc0, 0,0,0);
      acc1 = __builtin_amdgcn_mfma_f32_16x16x32_f16(arec[kk], bf[1][kk+8], acc1, 0,0,0);
      acc2 = __builtin_amdgcn_mfma_f32_16x16x32_f16(arec[kk], bf[2][kk+8], acc2, 0,0,0);
      acc3 = __builtin_amdgcn_mfma_f32_16x16x32_f16(arec[kk], bf[3][kk+8], acc3, 0,0,0);
    }

    // LSTM elementwise, fully in-register (i,f,g,o tiles share lane mapping)
    float hval[4];
#pragma unroll
    for (int r = 0; r < 4; ++r) {
      float si = sigmoidf_(acc0[r]);
      float sf = sigmoidf_(acc1[r]);
      float tg = tanhf_  (acc2[r]);
      float so = sigmoidf_(acc3[r]);
      float cn = sf*cst[r] + si*tg;
      cst[r] = cn;
      hval[r] = so*tanhf_(cn);
    }

    // publish h(t) slice (f16) to slot (t+1)&7
    _Float16* hw = hbufOwn + (size_t)((t+1) & 7)*(B_*H_) + c0 + lq;
#pragma unroll
    for (int r = 0; r < 4; ++r) {
      const int b = m*16 + quad*4 + r;
      hw[(size_t)b*H_] = (_Float16)hval[r];
    }
    if (layer == 1) {
      const int colg = dir*256 + c0 + lq;
#pragma unroll
      for (int r = 0; r < 4; ++r) {
        const int b = m*16 + quad*4 + r;
        out[((size_t)b*S_ + t)*(2*H_) + colg] = hval[r];
      }
      if (t == S_-1) {
#pragma unroll
        for (int r = 0; r < 4; ++r) {
          const int b = m*16 + quad*4 + r;
          out[OUT0 + (size_t)b*(2*H_) + colg] = hval[r];          // h_last
          out[OUT0 + B_*2*H_ + (size_t)b*(2*H_) + colg] = cst[r]; // c_last
        }
      }
    }
    if (lane == 0)
      __hip_atomic_store(myFlag, t+1, __ATOMIC_RELEASE, __HIP_MEMORY_SCOPE_AGENT);
  }
}

extern "C" void kernel_launch(void* const* d_in, const int* in_sizes, int n_in,
                              void* d_out, int out_size, void* d_ws, size_t ws_size,
                              hipStream_t stream) {
  const float* x     = (const float*)d_in[0];
  const float* enc_h = (const float*)d_in[1];
  const float* enc_c = (const float*)d_in[2];
  const float* Wih_f = (const float*)d_in[3];
  const float* Whh_f = (const float*)d_in[4];
  const float* bih_f = (const float*)d_in[5];
  const float* bhh_f = (const float*)d_in[6];
  const float* Wih_b = (const float*)d_in[7];
  const float* Whh_b = (const float*)d_in[8];
  const float* bih_b = (const float*)d_in[9];
  const float* bhh_b = (const float*)d_in[10];

  int* flags      = (int*)d_ws;
  _Float16* hbuf  = (_Float16*)((char*)d_ws + 8192);

  lstm_prep<<<64, 256, 0, stream>>>(enc_h, flags, hbuf);
  lstm_main<<<128, 64, 0, stream>>>(x, enc_c, Wih_f, Whh_f, bih_f, bhh_f,
                                    Wih_b, Whh_b, bih_b, bhh_b,
                                    (float*)d_out, flags, hbuf);
}

// Round 2
// 13819.882 us; speedup vs baseline: 1.2102x; 1.2102x over previous
//
#include <hip/hip_runtime.h>

// Bidirectional (feature-reversed) 2-layer LSTM, persistent-wave design.
// 4 chains = (dir, layer); each chain = 32 one-wave blocks (64 thr).
// Per wave: weights for 4 gate-tiles x K=512 resident in 256 VGPRs (f16),
// c-state in 4 VGPRs, per-tick: 16 A-frag loads + 64 mfma_f32_16x16x32_f16.
//
// R2: NO agent fences (they lower to buffer_inv/buffer_wbl2 = whole-L2
// maintenance per tick = the 8us/tick disaster of R1). All cross-block
// traffic is per-access coherent (relaxed SYSTEM-scope atomics -> sc0 sc1,
// served by the memory-side Infinity Cache). Ordering: data stores ->
// s_waitcnt vmcnt(0) -> flag store. Poll fan-in halved: m-halves decouple.

typedef _Float16 half8 __attribute__((ext_vector_type(8)));
typedef float f32x4 __attribute__((ext_vector_type(4)));

#define B_ 32
#define S_ 2048
#define D_ 256
#define H_ 256
#define G_ 1024
#define NSLOT 8
#define OUT0 (B_*S_*2*H_)   /* 33554432 */

__device__ __forceinline__ float sigmoidf_(float v){ return 1.f/(1.f+__expf(-v)); }
__device__ __forceinline__ float tanhf_(float v){ return 2.f/(1.f+__expf(-2.f*v)) - 1.f; }

union H8U { half8 h; unsigned u[4]; };

// 16B coherent load as 4 relaxed system-scope dword atomics (compiler-managed
// waitcnts; lowers to global_load_dword sc0 sc1 -> served from IF$, coherent).
__device__ __forceinline__ half8 ld_h8_sys(const _Float16* p) {
  const unsigned* u = (const unsigned*)p;
  H8U r;
  r.u[0] = __hip_atomic_load(u+0, __ATOMIC_RELAXED, __HIP_MEMORY_SCOPE_SYSTEM);
  r.u[1] = __hip_atomic_load(u+1, __ATOMIC_RELAXED, __HIP_MEMORY_SCOPE_SYSTEM);
  r.u[2] = __hip_atomic_load(u+2, __ATOMIC_RELAXED, __HIP_MEMORY_SCOPE_SYSTEM);
  r.u[3] = __hip_atomic_load(u+3, __ATOMIC_RELAXED, __HIP_MEMORY_SCOPE_SYSTEM);
  return r.h;
}

// ws layout: [0,8192): flags (4 chains * 32 members, 64B stride)
//            [8192, 8192+512KB): hbuf: 4 chains * 8 slots * (32*256) f16
__global__ __launch_bounds__(256) void lstm_prep(const float* __restrict__ enc_h,
                                                 int* __restrict__ flags,
                                                 _Float16* __restrict__ hbuf)
{
  int idx = blockIdx.x*blockDim.x + threadIdx.x;
  if (idx < 4*32)
    __hip_atomic_store(&flags[idx*16], 0, __ATOMIC_RELAXED, __HIP_MEMORY_SCOPE_SYSTEM);
  const int total = 4*B_*H_/2;
  for (int i = idx; i < total; i += gridDim.x*blockDim.x) {
    int di    = i*2;
    int chain = di >> 13;      // / (32*256)
    int r     = di & 8191;
    int b     = r >> 8;
    int col   = r & 255;
    int dir   = chain >> 1;
    _Float16 lo = (_Float16)enc_h[b*(2*H_) + dir*H_ + col];
    _Float16 hi = (_Float16)enc_h[b*(2*H_) + dir*H_ + col + 1];
    unsigned u = (unsigned)__builtin_bit_cast(unsigned short, lo)
               | ((unsigned)__builtin_bit_cast(unsigned short, hi) << 16);
    __hip_atomic_store((unsigned*)(hbuf + (size_t)chain*(NSLOT*B_*H_) + r), u,
                       __ATOMIC_RELAXED, __HIP_MEMORY_SCOPE_SYSTEM);
  }
}

__global__ __launch_bounds__(64,1) void lstm_main(
    const float* __restrict__ x,
    const float* __restrict__ enc_c,
    const float* __restrict__ Wih_f, const float* __restrict__ Whh_f,
    const float* __restrict__ bih_f, const float* __restrict__ bhh_f,
    const float* __restrict__ Wih_b, const float* __restrict__ Whh_b,
    const float* __restrict__ bih_b, const float* __restrict__ bhh_b,
    float* __restrict__ out,
    int* __restrict__ flags,
    _Float16* __restrict__ hbuf)
{
  const int bid   = blockIdx.x;   // 0..127
  const int chain = bid & 3;      // dir*2 + layer
  const int w     = bid >> 2;     // member 0..31
  const int dir   = chain >> 1;
  const int layer = chain & 1;
  const int m     = w & 1;        // M-tile (batch 16-row half)
  const int c0    = (w >> 1) << 4;// h-column base (16 cols)
  const int lane  = threadIdx.x;  // 64
  const int quad  = lane >> 4;
  const int lq    = lane & 15;

  const float* Wih = dir ? Wih_b : Wih_f;
  const float* Whh = dir ? Whh_b : Whh_f;
  const float* bih = dir ? bih_b : bih_f;
  const float* bhh = dir ? bhh_b : bhh_f;

  // ---- resident B-fragments: bf[q][kk], q=gate(i,f,g,o), kk=K-frag ----
  // B[k][n]: lane -> n = q*256 + c0 + lq, k = kk*32 + quad*8 + j (j=0..7)
  half8 bf[4][16];
#pragma unroll
  for (int q = 0; q < 4; ++q) {
    const int n_g = q*256 + c0 + lq;
    const float* wihr = Wih + (size_t)layer*G_*256 + (size_t)n_g*256 + quad*8;
    const float* whhr = Whh + (size_t)layer*G_*256 + (size_t)n_g*256 + quad*8;
#pragma unroll
    for (int kk = 0; kk < 16; ++kk) {
      const float* src = (kk < 8) ? (wihr + kk*32) : (whhr + (kk-8)*32);
      f32x4 w0 = *(const f32x4*)src;
      f32x4 w1 = *(const f32x4*)(src+4);
      half8 hv;
      hv[0]=(_Float16)w0[0]; hv[1]=(_Float16)w0[1]; hv[2]=(_Float16)w0[2]; hv[3]=(_Float16)w0[3];
      hv[4]=(_Float16)w1[0]; hv[5]=(_Float16)w1[1]; hv[6]=(_Float16)w1[2]; hv[7]=(_Float16)w1[3];
      bf[q][kk] = hv;
    }
  }

  float bias[4];
#pragma unroll
  for (int q = 0; q < 4; ++q) {
    const int n_g = q*256 + c0 + lq;
    bias[q] = bih[layer*G_ + n_g] + bhh[layer*G_ + n_g];
  }

  // c-state in C/D layout: row = m*16 + quad*4 + r, col = c0+lq
  f32x4 cst;
#pragma unroll
  for (int r = 0; r < 4; ++r) {
    const int b = m*16 + quad*4 + r;
    cst[r] = enc_c[b*(2*H_) + dir*H_ + c0 + lq];
  }

  _Float16* hbufOwn      = hbuf + (size_t)chain*(NSLOT*B_*H_);
  const _Float16* hbufL0 = hbuf + (size_t)(dir*2)*(NSLOT*B_*H_);
  int* myFlag = flags + (size_t)(chain*32 + w)*16;
  const int otherChain = (layer == 1) ? (dir*2) : (dir*2 + 1);

  // Poll set: only same-m members matter (m-halves are fully decoupled).
  // lanes: c16 = lane&15 indexes the 16 column-group members; grp selects
  // own-chain (h(t-1) ready) vs partner-chain (backpressure / producer).
  const int c16 = lane & 15;
  const int grp = (lane >> 4) & 1;
  const int spinChain = grp ? otherChain : chain;
  const int* spinPtr = flags + (size_t)(spinChain*32 + (m + 2*c16))*16;
  // L0: own >= t, L1(consumer) >= t-7 (slot backpressure)
  // L1: own >= t, L0(producer) >= t+1 (h0(t) published)
  const int tgtOff = (layer == 0) ? (grp ? -7 : 0) : (grp ? 1 : 0);

  const int arow = m*16 + lq;              // A-row (batch) this lane feeds
  const float* xrowBase = x + (size_t)arow*S_*D_;

  bool dead = false;

  for (int t = 0; t < S_; ++t) {
    half8 ain[8], arec[8];

    if (layer == 0) {
      // x loads issued BEFORE the flag wait (independent of recurrence)
      const float* xr = xrowBase + (size_t)t*D_;
#pragma unroll
      for (int kk = 0; kk < 8; ++kk) {
        const int k = kk*32 + quad*8;
        half8 hv;
        if (dir == 0) {
          f32x4 a0 = *(const f32x4*)(xr + k);
          f32x4 a1 = *(const f32x4*)(xr + k + 4);
          hv[0]=(_Float16)a0[0]; hv[1]=(_Float16)a0[1]; hv[2]=(_Float16)a0[2]; hv[3]=(_Float16)a0[3];
          hv[4]=(_Float16)a1[0]; hv[5]=(_Float16)a1[1]; hv[6]=(_Float16)a1[2]; hv[7]=(_Float16)a1[3];
        } else {
          // feature-reversed: u[k+j] = x[255-k-j] = p[7-j], p = xr + 248 - k
          const float* p = xr + (248 - k);
          f32x4 a0 = *(const f32x4*)p;
          f32x4 a1 = *(const f32x4*)(p + 4);
          hv[0]=(_Float16)a1[3]; hv[1]=(_Float16)a1[2]; hv[2]=(_Float16)a1[1]; hv[3]=(_Float16)a1[0];
          hv[4]=(_Float16)a0[3]; hv[5]=(_Float16)a0[2]; hv[6]=(_Float16)a0[1]; hv[7]=(_Float16)a0[0];
        }
        ain[kk] = hv;
      }
    }

    // ---- spin (no fences; relaxed system-scope polls, sc0 sc1) ----
    {
      const int tgt = t + tgtOff;
      int guard = 0;
      while (true) {
        int v = __hip_atomic_load(spinPtr, __ATOMIC_RELAXED, __HIP_MEMORY_SCOPE_SYSTEM);
        if (__all(v >= tgt)) break;
        if (++guard > (1 << 20)) { dead = true; break; }
      }
    }
    if (dead) break;
    asm volatile("" ::: "memory");   // pin data loads after the spin

    if (layer == 0) {
      const _Float16* hs = hbufOwn + (size_t)(t & 7)*(B_*H_) + (size_t)arow*H_ + quad*8;
#pragma unroll
      for (int kk = 0; kk < 8; ++kk)
        arec[kk] = ld_h8_sys(hs + kk*32);
    } else {
      const _Float16* hi = hbufL0 + (size_t)((t+1) & 7)*(B_*H_) + (size_t)arow*H_ + quad*8;
      const _Float16* hr = hbufOwn + (size_t)(t & 7)*(B_*H_) + (size_t)arow*H_ + quad*8;
#pragma unroll
      for (int kk = 0; kk < 8; ++kk) {
        ain[kk]  = ld_h8_sys(hi + kk*32);
        arec[kk] = ld_h8_sys(hr + kk*32);
      }
    }

    f32x4 acc0 = {bias[0],bias[0],bias[0],bias[0]};
    f32x4 acc1 = {bias[1],bias[1],bias[1],bias[1]};
    f32x4 acc2 = {bias[2],bias[2],bias[2],bias[2]};
    f32x4 acc3 = {bias[3],bias[3],bias[3],bias[3]};
#pragma unroll
    for (int kk = 0; kk < 8; ++kk) {
      acc0 = __builtin_amdgcn_mfma_f32_16x16x32_f16(ain[kk], bf[0][kk], acc0, 0,0,0);
      acc1 = __builtin_amdgcn_mfma_f32_16x16x32_f16(ain[kk], bf[1][kk], acc1, 0,0,0);
      acc2 = __builtin_amdgcn_mfma_f32_16x16x32_f16(ain[kk], bf[2][kk], acc2, 0,0,0);
      acc3 = __builtin_amdgcn_mfma_f32_16x16x32_f16(ain[kk], bf[3][kk], acc3, 0,0,0);
    }
#pragma unroll
    for (int kk = 0; kk < 8; ++kk) {
      acc0 = __builtin_amdgcn_mfma_f32_16x16x32_f16(arec[kk], bf[0][kk+8], acc0, 0,0,0);
      acc1 = __builtin_amdgcn_mfma_f32_16x16x32_f16(arec[kk], bf[1][kk+8], acc1, 0,0,0);
      acc2 = __builtin_amdgcn_mfma_f32_16x16x32_f16(arec[kk], bf[2][kk+8], acc2, 0,0,0);
      acc3 = __builtin_amdgcn_mfma_f32_16x16x32_f16(arec[kk], bf[3][kk+8], acc3, 0,0,0);
    }

    // LSTM elementwise, fully in-register (i,f,g,o tiles share lane mapping)
    float hval[4];
#pragma unroll
    for (int r = 0; r < 4; ++r) {
      float si = sigmoidf_(acc0[r]);
      float sf = sigmoidf_(acc1[r]);
      float tg = tanhf_  (acc2[r]);
      float so = sigmoidf_(acc3[r]);
      float cn = sf*cst[r] + si*tg;
      cst[r] = cn;
      hval[r] = so*tanhf_(cn);
    }

    // publish h(t) slice (f16) to slot (t+1)&7 — packed to dwords via
    // shfl_xor so all coherent stores are 4B (global_store_dword sc0 sc1)
    _Float16* hw = hbufOwn + (size_t)((t+1) & 7)*(B_*H_) + c0 + lq;
#pragma unroll
    for (int r = 0; r < 4; ++r) {
      float partner = __shfl_xor(hval[r], 1);
      if (!(lq & 1)) {
        unsigned short lo = __builtin_bit_cast(unsigned short, (_Float16)hval[r]);
        unsigned short hi = __builtin_bit_cast(unsigned short, (_Float16)partner);
        unsigned u = (unsigned)lo | ((unsigned)hi << 16);
        const int b = m*16 + quad*4 + r;
        __hip_atomic_store((unsigned*)(hw + (size_t)b*H_), u,
                           __ATOMIC_RELAXED, __HIP_MEMORY_SCOPE_SYSTEM);
      }
    }
    // drain publish stores to the coherence point, then raise the flag
    asm volatile("s_waitcnt vmcnt(0)" ::: "memory");
    if (lane == 0)
      __hip_atomic_store(myFlag, t+1, __ATOMIC_RELAXED, __HIP_MEMORY_SCOPE_SYSTEM);

    // out[] stores AFTER the flag publish — off the critical path
    if (layer == 1) {
      const int colg = dir*256 + c0 + lq;
#pragma unroll
      for (int r = 0; r < 4; ++r) {
        const int b = m*16 + quad*4 + r;
        out[((size_t)b*S_ + t)*(2*H_) + colg] = hval[r];
      }
      if (t == S_-1) {
#pragma unroll
        for (int r = 0; r < 4; ++r) {
          const int b = m*16 + quad*4 + r;
          out[OUT0 + (size_t)b*(2*H_) + colg] = hval[r];          // h_last
          out[OUT0 + B_*2*H_ + (size_t)b*(2*H_) + colg] = cst[r]; // c_last
        }
      }
    }
  }
}

extern "C" void kernel_launch(void* const* d_in, const int* in_sizes, int n_in,
                              void* d_out, int out_size, void* d_ws, size_t ws_size,
                              hipStream_t stream) {
  const float* x     = (const float*)d_in[0];
  const float* enc_h = (const float*)d_in[1];
  const float* enc_c = (const float*)d_in[2];
  const float* Wih_f = (const float*)d_in[3];
  const float* Whh_f = (const float*)d_in[4];
  const float* bih_f = (const float*)d_in[5];
  const float* bhh_f = (const float*)d_in[6];
  const float* Wih_b = (const float*)d_in[7];
  const float* Whh_b = (const float*)d_in[8];
  const float* bih_b = (const float*)d_in[9];
  const float* bhh_b = (const float*)d_in[10];

  int* flags      = (int*)d_ws;
  _Float16* hbuf  = (_Float16*)((char*)d_ws + 8192);

  lstm_prep<<<64, 256, 0, stream>>>(enc_h, flags, hbuf);
  lstm_main<<<128, 64, 0, stream>>>(x, enc_c, Wih_f, Whh_f, bih_f, bhh_f,
                                    Wih_b, Whh_b, bih_b, bhh_b,
                                    (float*)d_out, flags, hbuf);
}